// Round 2
// baseline (155.514 us; speedup 1.0000x reference)
//
#include <hip/hip_runtime.h>
#include <stdint.h>

typedef unsigned short u16;
typedef __attribute__((ext_vector_type(8))) short short8;
typedef __attribute__((ext_vector_type(4))) float f32x4;

#define MFMA16(a, b, c) __builtin_amdgcn_mfma_f32_16x16x32_bf16((a), (b), (c), 0, 0, 0)

__device__ __forceinline__ u16 f2bf(float f) {
  unsigned int u = __float_as_uint(f);
  u += 0x7FFFu + ((u >> 16) & 1u);
  return (u16)(u >> 16);
}

__device__ __forceinline__ void gload16(const u16* g, u16* lds) {
  __builtin_amdgcn_global_load_lds(
      (const __attribute__((address_space(1))) unsigned int*)g,
      (__attribute__((address_space(3))) unsigned int*)lds, 16, 0, 0);
}

// ---------------- conversions ----------------
__global__ void cvt_bf16_kernel(const float* __restrict__ in, u16* __restrict__ out, int n4) {
  int i = blockIdx.x * blockDim.x + threadIdx.x;
  int stride = gridDim.x * blockDim.x;
  for (; i < n4; i += stride) {
    float4 v = ((const float4*)in)[i];
    ushort4 o;
    o.x = f2bf(v.x); o.y = f2bf(v.y); o.z = f2bf(v.z); o.w = f2bf(v.w);
    ((ushort4*)out)[i] = o;
  }
}

// src is R x C fp32 row-major; dst is C x R bf16 row-major: dst[c][r] = src[r][c]*scale
__global__ void trans_cvt(const float* __restrict__ src, u16* __restrict__ dst,
                          int R, int C, float scale) {
  __shared__ float tile[32][33];
  int bx = blockIdx.x * 32, by = blockIdx.y * 32;
  int tx = threadIdx.x, ty = threadIdx.y;  // block (32,8)
#pragma unroll
  for (int i = 0; i < 4; ++i)
    tile[ty + 8 * i][tx] = src[(size_t)(by + ty + 8 * i) * C + bx + tx];
  __syncthreads();
#pragma unroll
  for (int i = 0; i < 4; ++i)
    dst[(size_t)(bx + ty + 8 * i) * R + by + tx] = f2bf(tile[tx][ty + 8 * i] * scale);
}

// V transpose: vhb [bh][j=512][c=64] -> vtb [bh][c=64][j=512]
__global__ void vtrans_kernel(const u16* __restrict__ vhb, u16* __restrict__ vtb) {
  __shared__ u16 tile[64][65];
  int bh = blockIdx.y, j0 = blockIdx.x * 64;
  int tx = threadIdx.x, ty = threadIdx.y;  // block (64,8)
  const u16* src = vhb + (size_t)bh * 512 * 64;
#pragma unroll
  for (int k = 0; k < 8; ++k)
    tile[ty + k * 8][tx] = src[(size_t)(j0 + ty + k * 8) * 64 + tx];
  __syncthreads();
  u16* dst = vtb + (size_t)bh * 64 * 512;
#pragma unroll
  for (int k = 0; k < 8; ++k)
    dst[(size_t)(ty + k * 8) * 512 + j0 + tx] = tile[tx][ty + k * 8];
}

// ---------------- GEMM: C[M][N] = A[M][K] * BT[N][K]^T ----------------
// 128x128 tile, BK=32, 256 threads (4 waves 2x2), global_load_lds staging.
// MODE 0: f32 row-major to C0. MODE 1: bf16 per-head [b][h][2048][64] (N=512).
// MODE 2: bf16 per-head split K|V: cols<512 -> C0 [b][h][512][64], else C1.
template <int MODE>
__global__ __launch_bounds__(256) void gemm_bt(const u16* __restrict__ A,
                                               const u16* __restrict__ BT,
                                               void* __restrict__ C0p,
                                               void* __restrict__ C1p,
                                               int M, int N, int K) {
  __shared__ __align__(16) u16 As[128 * 32];
  __shared__ __align__(16) u16 Bs[128 * 32];
  const int t = threadIdx.x;
  const int w = t >> 6, l = t & 63, lr = l & 15, lg = l >> 4;
  const int wr = w >> 1, wc = w & 1;
  const int tm = blockIdx.y * 128, tn = blockIdx.x * 128;

  f32x4 acc[4][4];
#pragma unroll
  for (int mi = 0; mi < 4; ++mi)
#pragma unroll
    for (int ni = 0; ni < 4; ++ni) acc[mi][ni] = (f32x4){0.f, 0.f, 0.f, 0.f};

  for (int kt = 0; kt < K; kt += 32) {
#pragma unroll
    for (int p = 0; p < 2; ++p) {
      int ci = p * 256 + t;
      int row = ci >> 2, c8 = ci & 3;
      int ldsoff = (p * 256 + (t & 192)) * 8;  // wave-uniform base chunk
      gload16(A + (size_t)(tm + row) * K + kt + c8 * 8, As + ldsoff);
      gload16(BT + (size_t)(tn + row) * K + kt + c8 * 8, Bs + ldsoff);
    }
    __syncthreads();
    short8 af[4], bf[4];
#pragma unroll
    for (int mi = 0; mi < 4; ++mi)
      af[mi] = *(const short8*)&As[(wr * 64 + mi * 16 + lr) * 32 + lg * 8];
#pragma unroll
    for (int ni = 0; ni < 4; ++ni)
      bf[ni] = *(const short8*)&Bs[(wc * 64 + ni * 16 + lr) * 32 + lg * 8];
#pragma unroll
    for (int mi = 0; mi < 4; ++mi)
#pragma unroll
      for (int ni = 0; ni < 4; ++ni)
        acc[mi][ni] = MFMA16(af[mi], bf[ni], acc[mi][ni]);
    __syncthreads();
  }

#pragma unroll
  for (int mi = 0; mi < 4; ++mi)
#pragma unroll
    for (int ni = 0; ni < 4; ++ni)
#pragma unroll
      for (int r = 0; r < 4; ++r) {
        int rg = tm + wr * 64 + mi * 16 + lg * 4 + r;
        int cg = tn + wc * 64 + ni * 16 + lr;
        float val = acc[mi][ni][r];
        if (MODE == 0) {
          ((float*)C0p)[(size_t)rg * N + cg] = val;
        } else if (MODE == 1) {
          ((u16*)C0p)[(((size_t)(rg >> 11) * 8 + (cg >> 6)) * 2048 + (rg & 2047)) * 64 +
                      (cg & 63)] = f2bf(val);
        } else {
          int cc = cg & 511;
          u16* d = (cg < 512) ? (u16*)C0p : (u16*)C1p;
          d[(((size_t)(rg >> 9) * 8 + (cc >> 6)) * 512 + (rg & 511)) * 64 + (cc & 63)] =
              f2bf(val);
        }
      }
}

// ---------------- attention ----------------
// grid (bh=32, qt=32); block 256 = 4 waves, 16 q-rows per wave.
// qhb: [bh][2048][64] (pre-scaled by 1/8 via Wq). khb: [bh][512][64].
// vtb: [bh][64][512] (V^T). aob: [b*2048+i][512] row-major.
// Swapped QK^T: mfma(K_frag, Q_frag) -> lane (i=l&15, g=l>>4) holds
// S[qrow i][j = jt*16 + g*4 + r] for jt=0..31 (full 512 j per q-row,
// distributed over 4 g-groups). Softmax lane-local + shfl_xor(16,32).
__global__ __launch_bounds__(256, 3) void attn_kernel(const u16* __restrict__ qhb,
                                                      const u16* __restrict__ khb,
                                                      const u16* __restrict__ vtb,
                                                      u16* __restrict__ aob) {
  __shared__ __align__(16) u16 pl[4][16 * 256];  // per-wave P half-panel [16 i][256 j]
  const int t = threadIdx.x, w = t >> 6, l = t & 63, i = l & 15, g = l >> 4;
  const int bh = blockIdx.x, qt = blockIdx.y;

  const u16* qp = qhb + ((size_t)bh * 2048 + qt * 64 + w * 16) * 64;
  const u16* kp = khb + (size_t)bh * 512 * 64;
  const u16* vp = vtb + (size_t)bh * 64 * 512;

  short8 qa0 = *(const short8*)(qp + (size_t)i * 64 + g * 8);
  short8 qa1 = *(const short8*)(qp + (size_t)i * 64 + 32 + g * 8);

  // QK^T (swapped): 64 dense 16B loads from L2-resident K panel + 64 MFMA.
  f32x4 sc[32];
#pragma unroll
  for (int jt = 0; jt < 32; ++jt) {
    const u16* kr = kp + (size_t)(jt * 16 + i) * 64 + g * 8;
    short8 k0 = *(const short8*)kr;
    short8 k1 = *(const short8*)(kr + 32);
    f32x4 a = (f32x4){0.f, 0.f, 0.f, 0.f};
    a = MFMA16(k0, qa0, a);
    a = MFMA16(k1, qa1, a);
    sc[jt] = a;
  }

  // softmax: lane-local over 128 values, then combine 4 g-groups.
  f32x4 vm = sc[0];
#pragma unroll
  for (int jt = 1; jt < 32; ++jt) {
#pragma unroll
    for (int r = 0; r < 4; ++r) vm[r] = fmaxf(vm[r], sc[jt][r]);
  }
  float mx = fmaxf(fmaxf(vm[0], vm[1]), fmaxf(vm[2], vm[3]));
  mx = fmaxf(mx, __shfl_xor(mx, 16));
  mx = fmaxf(mx, __shfl_xor(mx, 32));
  float sum = 0.f;
#pragma unroll
  for (int jt = 0; jt < 32; ++jt) {
#pragma unroll
    for (int r = 0; r < 4; ++r) {
      float e = __expf(sc[jt][r] - mx);
      sc[jt][r] = e;
      sum += e;
    }
  }
  sum += __shfl_xor(sum, 16);
  sum += __shfl_xor(sum, 32);
  float inv = 1.f / sum;

  // PV: per half, pack P to bf16 (cvt_pk) -> swizzled wave-private LDS ->
  // read A-frags; V^T B-frags straight from L2. No barriers anywhere.
  u16* pw = pl[w];
  f32x4 oac[4];
#pragma unroll
  for (int ct = 0; ct < 4; ++ct) oac[ct] = (f32x4){0.f, 0.f, 0.f, 0.f};

#pragma unroll
  for (int half = 0; half < 2; ++half) {
#pragma unroll
    for (int tt = 0; tt < 16; ++tt) {
      int jt = half * 16 + tt;
      unsigned w0, w1;
      asm("v_cvt_pk_bf16_f32 %0, %1, %2" : "=v"(w0) : "v"(sc[jt][0]), "v"(sc[jt][1]));
      asm("v_cvt_pk_bf16_f32 %0, %1, %2" : "=v"(w1) : "v"(sc[jt][2]), "v"(sc[jt][3]));
      int col = (tt * 16 + g * 4) ^ ((i & 7) << 3);
      uint2 pk2; pk2.x = w0; pk2.y = w1;
      *(uint2*)&pw[i * 256 + col] = pk2;
    }
#pragma unroll
    for (int T = 0; T < 8; ++T) {
      int colr = (T * 32 + g * 8) ^ ((i & 7) << 3);
      short8 pa = *(const short8*)&pw[i * 256 + colr];
#pragma unroll
      for (int ct = 0; ct < 4; ++ct) {
        short8 vf = *(const short8*)(vp + (size_t)(ct * 16 + i) * 512 + half * 256 + T * 32 + g * 8);
        oac[ct] = MFMA16(pa, vf, oac[ct]);
      }
    }
  }

  // epilogue: redistribute 1/sum to the lanes holding each output row, store.
  float iv[4];
#pragma unroll
  for (int r = 0; r < 4; ++r) iv[r] = __shfl(inv, (l & 48) + g * 4 + r);
  u16* op = aob + ((size_t)(bh >> 3) * 2048 + qt * 64 + w * 16) * 512 + (bh & 7) * 64;
#pragma unroll
  for (int ct = 0; ct < 4; ++ct)
#pragma unroll
    for (int r = 0; r < 4; ++r)
      op[(size_t)(g * 4 + r) * 512 + ct * 16 + i] = f2bf(oac[ct][r] * iv[r]);
}

// ---------------- launch ----------------
extern "C" void kernel_launch(void* const* d_in, const int* in_sizes, int n_in,
                              void* d_out, int out_size, void* d_ws, size_t ws_size,
                              hipStream_t stream) {
  const float* x  = (const float*)d_in[0];  // [4,2048,1024]
  const float* cx = (const float*)d_in[1];  // [4,512,768]
  const float* Wq = (const float*)d_in[2];  // [1024,512]
  const float* Wk = (const float*)d_in[3];  // [768,512]
  const float* Wv = (const float*)d_in[4];  // [768,512]
  const float* Wo = (const float*)d_in[5];  // [512,1024]
  float* out = (float*)d_out;               // [4,2048,1024]

  char* p = (char*)d_ws;
  u16* xb   = (u16*)p; p += (size_t)8388608 * 2;   // x bf16
  u16* cb   = (u16*)p; p += (size_t)1572864 * 2;   // context bf16
  u16* wqT  = (u16*)p; p += (size_t)524288 * 2;    // Wq^T * 0.125   [512][1024]
  u16* wkvT = (u16*)p; p += (size_t)786432 * 2;    // [Wk^T; Wv^T]   [1024][768]
  u16* woT  = (u16*)p; p += (size_t)524288 * 2;    // Wo^T           [1024][512]
  u16* qhb  = (u16*)p; p += (size_t)4194304 * 2;   // q  [bh][2048][64]
  u16* khb  = (u16*)p; p += (size_t)1048576 * 2;   // k  [bh][512][64]
  u16* vhb  = (u16*)p; p += (size_t)1048576 * 2;   // v  [bh][512][64]
  u16* vtb  = (u16*)p; p += (size_t)1048576 * 2;   // v^T [bh][64][512]
  u16* aob  = (u16*)p; p += (size_t)4194304 * 2;   // attn out [8192][512]

  cvt_bf16_kernel<<<2048, 256, 0, stream>>>(x, xb, 8388608 / 4);
  cvt_bf16_kernel<<<1024, 256, 0, stream>>>(cx, cb, 1572864 / 4);
  trans_cvt<<<dim3(512 / 32, 1024 / 32), dim3(32, 8), 0, stream>>>(Wq, wqT, 1024, 512, 0.125f);
  trans_cvt<<<dim3(512 / 32, 768 / 32), dim3(32, 8), 0, stream>>>(Wk, wkvT, 768, 512, 1.0f);
  trans_cvt<<<dim3(512 / 32, 768 / 32), dim3(32, 8), 0, stream>>>(Wv, wkvT + (size_t)512 * 768, 768, 512, 1.0f);
  trans_cvt<<<dim3(1024 / 32, 512 / 32), dim3(32, 8), 0, stream>>>(Wo, woT, 512, 1024, 1.0f);

  gemm_bt<1><<<dim3(4, 64), 256, 0, stream>>>(xb, wqT, qhb, nullptr, 8192, 512, 1024);
  gemm_bt<2><<<dim3(8, 16), 256, 0, stream>>>(cb, wkvT, khb, vhb, 2048, 1024, 768);
  vtrans_kernel<<<dim3(8, 32), dim3(64, 8), 0, stream>>>(vhb, vtb);
  attn_kernel<<<dim3(32, 32), 256, 0, stream>>>(qhb, khb, vtb, aob);
  gemm_bt<0><<<dim3(8, 64), 256, 0, stream>>>(aob, woT, out, nullptr, 8192, 1024, 512);
}